// Round 8
// baseline (182.997 us; speedup 1.0000x reference)
//
#include <hip/hip_runtime.h>
#include <hip/hip_bf16.h>

#define H_ 4
#define B_ 16
#define T_ 4000
#define E_ 512
#define D_ 512
#define A_ 128
#define C_ 10
#define K_ 101
#define O_ 512
#define TC_ 50
#define CH_ (T_ / TC_)   // 80

typedef __attribute__((ext_vector_type(16))) float f32x16;
typedef __attribute__((ext_vector_type(8)))  short short8;

#define MFMA32(a, b, c) __builtin_amdgcn_mfma_f32_32x32x16_bf16(a, b, c, 0, 0, 0)

#define GLL16(gp, lp) __builtin_amdgcn_global_load_lds( \
    (const __attribute__((address_space(1))) unsigned int*)(gp), \
    (__attribute__((address_space(3))) unsigned int*)(lp), 16, 0, 0)

static __device__ __forceinline__ unsigned short f2bf(float x) {
  unsigned u = __float_as_uint(x);
  unsigned r = (u + 0x7FFFu + ((u >> 16) & 1u)) >> 16;
  return (unsigned short)r;
}
static __device__ __forceinline__ unsigned pk2(float a, float b) {
  return (unsigned)f2bf(a) | ((unsigned)f2bf(b) << 16);
}
// single-instruction packed f32x2 -> bf16x2 (RNE)
static __device__ __forceinline__ unsigned cvtpk(float lo, float hi) {
  unsigned r;
  asm("v_cvt_pk_bf16_f32 %0, %1, %2" : "=v"(r) : "v"(lo), "v"(hi));
  return r;
}
static __device__ __forceinline__ short8 pack8(float4 a, float4 b) {
  uint4 u;
  u.x = cvtpk(a.x, a.y); u.y = cvtpk(a.z, a.w);
  u.z = cvtpk(b.x, b.y); u.w = cvtpk(b.z, b.w);
  short8 r;
  __builtin_memcpy(&r, &u, 16);
  return r;
}
static __device__ __forceinline__ f32x16 zero16() {
  f32x16 z;
#pragma unroll
  for (int i = 0; i < 16; ++i) z[i] = 0.f;
  return z;
}
static __device__ __forceinline__ float tanh_fast(float x) {
  return 1.0f - 2.0f / (__expf(2.0f * x) + 1.0f);
}
// swizzled byte offset for 32-k-wide bf16 tiles packed as 2 rows per 128B line
static __device__ __forceinline__ int swz32(int r, int ksg) {
  return (r >> 1) * 128 + (((((r & 1) << 2) | ksg) ^ ((r >> 1) & 7)) << 4);
}

// ---------------------------------------------------------------------------
// k_prep: (a) wbs = pre-swizzled bf16 Wenc [16 kt][512 n][32 k]; each head's
// 128 cols of a kt-slab is a contiguous 8KB block. (b) wattb = pre-swizzled
// bf16 padded Watt [h][128 a][16 k] (4KB/head). (c) addv4 = 4-way split-K
// partials of benc + dec_z@Wdec, layout [p][b][h][a].
__global__ __launch_bounds__(256) void k_prep(const float* __restrict__ Wenc,
                                              const float* __restrict__ Watt,
                                              const float* __restrict__ dec_z,
                                              const float* __restrict__ Wdec,
                                              const float* __restrict__ benc,
                                              char* __restrict__ wbs,
                                              char* __restrict__ wattb,
                                              float* __restrict__ addv4) {
  const int bid = blockIdx.x;
  const int tid = threadIdx.x;
  if (bid < 128) {
    const int c = bid * 256 + tid;          // 16B chunk index into wbs
    const int cc = c & 2047;
    const int kt = c >> 11;
    const int line = cc >> 3, sp = cc & 7;
    const int sraw = sp ^ (line & 7);
    const int n = line * 2 + (sraw >> 2);
    const int ksg = sraw & 3;
    const int h = n >> 7, a = n & 127;
    const int kb = kt * 32 + ksg * 8;
    uint4 u;
    u.x = pk2(Wenc[((size_t)h * E_ + kb + 0) * A_ + a], Wenc[((size_t)h * E_ + kb + 1) * A_ + a]);
    u.y = pk2(Wenc[((size_t)h * E_ + kb + 2) * A_ + a], Wenc[((size_t)h * E_ + kb + 3) * A_ + a]);
    u.z = pk2(Wenc[((size_t)h * E_ + kb + 4) * A_ + a], Wenc[((size_t)h * E_ + kb + 5) * A_ + a]);
    u.w = pk2(Wenc[((size_t)h * E_ + kb + 6) * A_ + a], Wenc[((size_t)h * E_ + kb + 7) * A_ + a]);
    ((uint4*)wbs)[c] = u;
  } else if (bid == 128) {
#pragma unroll
    for (int q = 0; q < 4; ++q) {
      const int cw = q * 256 + tid;
      const int h = cw >> 8, cc = cw & 255;
      const int line = cc >> 3, sp = cc & 7;
      const int sraw = sp ^ (line & 7);
      const int a = line * 4 + (sraw >> 1);
      const int s = sraw & 1;
      unsigned short v[8];
#pragma unroll
      for (int j = 0; j < 8; ++j) {
        const int k = s * 8 + j;
        v[j] = (k < C_) ? f2bf(Watt[((size_t)h * C_ + k) * A_ + a]) : (unsigned short)0;
      }
      uint4 u;
      u.x = (unsigned)v[0] | ((unsigned)v[1] << 16);
      u.y = (unsigned)v[2] | ((unsigned)v[3] << 16);
      u.z = (unsigned)v[4] | ((unsigned)v[5] << 16);
      u.w = (unsigned)v[6] | ((unsigned)v[7] << 16);
      ((uint4*)wattb)[cw] = u;
    }
  } else {
    const int idx = bid - 129;
    const int b = idx >> 3, h = (idx >> 1) & 3, ks = idx & 1;
    const int a = tid & 127, kh = tid >> 7;
    const int p = ks * 2 + kh;
    const int d0 = p * 128;
    const float* z = dec_z + (size_t)b * D_ + d0;
    const float* w = Wdec + ((size_t)h * D_ + d0) * A_ + a;
    float s = (p == 0) ? benc[h * A_ + a] : 0.f;
#pragma unroll 8
    for (int d = 0; d < 128; ++d) s += z[d] * w[(size_t)d * A_];
    addv4[(((size_t)p * B_ + b) * H_ + h) * A_ + a] = s;
  }
}

// ---------------------------------------------------------------------------
__global__ __launch_bounds__(256) void k_conv(const float* __restrict__ att_prev,
                                              const float* __restrict__ conv_w,
                                              char* __restrict__ convpad) {
  const int bh = blockIdx.x;
  const int b = bh / H_, h = bh % H_;
  const int t0 = blockIdx.y * 256;
  __shared__ float ap[256 + K_ - 1 + 3];
  __shared__ float cw[C_ * K_];
  const float* src = att_prev + ((size_t)h * B_ + b) * T_;
  for (int i = threadIdx.x; i < 256 + K_ - 1; i += 256) {
    int tt = t0 - (K_ / 2) + i;
    ap[i] = (tt >= 0 && tt < T_) ? src[tt] : 0.f;
  }
  for (int i = threadIdx.x; i < C_ * K_; i += 256) cw[i] = conv_w[(size_t)h * C_ * K_ + i];
  __syncthreads();
  const int t = t0 + threadIdx.x;
  if (t < T_) {
    float s[C_];
#pragma unroll
    for (int c = 0; c < C_; ++c) s[c] = 0.f;
    for (int k = 0; k < K_; ++k) {
      float apv = ap[threadIdx.x + k];
#pragma unroll
      for (int c = 0; c < C_; ++c) s[c] += cw[c * K_ + k] * apv;
    }
    uint4 u0, u1;
    u0.x = pk2(s[0], s[1]); u0.y = pk2(s[2], s[3]);
    u0.z = pk2(s[4], s[5]); u0.w = pk2(s[6], s[7]);
    u1.x = pk2(s[8], s[9]); u1.y = 0u; u1.z = 0u; u1.w = 0u;
    char* dst = convpad + (size_t)(b * T_ + t) * 128 + h * 32;
    *(uint4*)dst = u0;
    *(uint4*)(dst + 16) = u1;
  }
}

// ---------------------------------------------------------------------------
// Fused MFMA, B-RESIDENT / BARRIER-FREE K-LOOP.
// Block = 1 head x 512 rows (grid 500 = 125 slices x 4 heads, head-adjacent
// so the 4 heads of a slice share enc via L3/L2). 8 waves, each 64 rows x
// 128 cols -> acc[2][4] = 128 AGPRs.
// All 16 B-slabs (128KB) + Watt (4KB) staged to LDS ONCE via GLL16, a single
// __syncthreads, then the K-loop has NO barriers: each lane direct-loads its
// own A-fragments from enc (lane hi=0/1 pairs cover rows contiguously ->
// no over-fetch), packs via v_cvt_pk_bf16_f32, reads resident B-frags.
// Rounds 2-7 all hit a ~87us wall from the per-kt barrier-coupled staging
// chain (GLL 32KB -> vmcnt -> s_barrier -> LDS reads) regardless of tile
// shape/occupancy/pipelining; this removes that chain entirely.
__global__ __launch_bounds__(512, 2) void k_fused_e_mfma(
    const float* __restrict__ enc,
    const char*  __restrict__ wbs,
    const char*  __restrict__ convpad,
    const char*  __restrict__ wattb,
    const float* __restrict__ addv4,
    const float* __restrict__ gv,
    float* __restrict__ e_out) {
  __shared__ char smem[135168];   // 16 x 8KB B-slabs + 4KB Watt
  const int tid = threadIdx.x;
  const int wv = tid >> 6;
  const int lane = tid & 63;
  const int ln31 = lane & 31;
  const int hi = lane >> 5;
  const int h = blockIdx.x & 3;
  const int m0 = (blockIdx.x >> 2) * 512;

  f32x16 acc[2][4];
#pragma unroll
  for (int i = 0; i < 2; ++i)
#pragma unroll
    for (int j = 0; j < 4; ++j) acc[i][j] = zero16();

  // ---- one-time staging: B (16 slabs x 8KB) + Watt (4KB)
#pragma unroll
  for (int kt = 0; kt < 16; ++kt)
    GLL16(wbs + (size_t)kt * 32768 + h * 8192 + wv * 1024 + lane * 16,
          smem + kt * 8192 + wv * 1024);
  if (wv < 4)
    GLL16(wattb + h * 4096 + wv * 1024 + lane * 16, smem + 131072 + wv * 1024);

  // per-lane A geometry: rows r0,r1; k-base hi*8 (frag = 8 consecutive k)
  const int r0 = m0 + wv * 64 + ln31;
  const int r1 = r0 + 32;
  const float* eR0 = enc + (size_t)r0 * E_ + hi * 8;
  const float* eR1 = enc + (size_t)r1 * E_ + hi * 8;
  int boff[4];
#pragma unroll
  for (int ni = 0; ni < 4; ++ni) boff[ni] = swz32(ni * 32 + ln31, hi);

  // issue first A loads before the barrier (independent of LDS)
  float4 f00 = ((const float4*)eR0)[0];
  float4 f01 = ((const float4*)eR0)[1];
  float4 f02 = ((const float4*)eR0)[4];
  float4 f03 = ((const float4*)eR0)[5];
  float4 f10 = ((const float4*)eR1)[0];
  float4 f11 = ((const float4*)eR1)[1];
  float4 f12 = ((const float4*)eR1)[4];
  float4 f13 = ((const float4*)eR1)[5];

  __syncthreads();   // the ONLY block-wide barrier

  // ---- barrier-free K-loop: 16 kt, BK=32 (2 MFMA k-halves)
#pragma unroll 2
  for (int kt = 0; kt < 16; ++kt) {
    short8 a00 = pack8(f00, f01);   // r0, k-half 0
    short8 a01 = pack8(f02, f03);   // r0, k-half 1
    short8 a10 = pack8(f10, f11);   // r1, k-half 0
    short8 a11 = pack8(f12, f13);   // r1, k-half 1
    if (kt < 15) {
      const float4* p0 = (const float4*)eR0 + (kt + 1) * 8;
      const float4* p1 = (const float4*)eR1 + (kt + 1) * 8;
      f00 = p0[0]; f01 = p0[1]; f02 = p0[4]; f03 = p0[5];
      f10 = p1[0]; f11 = p1[1]; f12 = p1[4]; f13 = p1[5];
    }
    const char* pB = smem + kt * 8192;
#pragma unroll
    for (int ni = 0; ni < 4; ++ni) {
      short8 b0_ = *(const short8*)(pB + boff[ni]);
      acc[0][ni] = MFMA32(a00, b0_, acc[0][ni]);
      acc[1][ni] = MFMA32(a10, b0_, acc[1][ni]);
    }
#pragma unroll
    for (int ni = 0; ni < 4; ++ni) {
      short8 b1_ = *(const short8*)(pB + (boff[ni] ^ 32));
      acc[0][ni] = MFMA32(a01, b1_, acc[0][ni]);
      acc[1][ni] = MFMA32(a11, b1_, acc[1][ni]);
    }
  }

  // ---- conv MFMA step (K=16): A frags direct from convpad, B = Watt (LDS)
  {
    short8 c0 = *(const short8*)(convpad + (size_t)r0 * 128 + h * 32 + hi * 16);
    short8 c1 = *(const short8*)(convpad + (size_t)r1 * 128 + h * 32 + hi * 16);
    const char* WattL = smem + 131072;
#pragma unroll
    for (int ni = 0; ni < 4; ++ni) {
      const int ar = ni * 32 + ln31;
      short8 wf = *(const short8*)(WattL + (ar >> 2) * 128 +
                                   (((((ar & 3) << 1) | hi) ^ ((ar >> 2) & 7)) << 4));
      acc[0][ni] = MFMA32(c0, wf, acc[0][ni]);
      acc[1][ni] = MFMA32(c1, wf, acc[1][ni]);
    }
  }

  // ---- epilogue: + addv, tanh, dot gv, 32-lane reduce, store e
  {
    const int wr0 = m0 + wv * 64;
    const unsigned b0w = (unsigned)wr0 / 4000u;
    const unsigned b1w = (unsigned)(wr0 + 63) / 4000u;
    float av0[4], av1[4], gvr[4];
#pragma unroll
    for (int ni = 0; ni < 4; ++ni) {
      const int a = ni * 32 + ln31;
      const int i0 = (int)b0w * 512 + h * 128 + a;
      const int i1 = (int)b1w * 512 + h * 128 + a;
      av0[ni] = addv4[i0] + addv4[8192 + i0] + addv4[16384 + i0] + addv4[24576 + i0];
      av1[ni] = addv4[i1] + addv4[8192 + i1] + addv4[16384 + i1] + addv4[24576 + i1];
      gvr[ni] = gv[h * 128 + a];
    }
#pragma unroll
    for (int mi = 0; mi < 2; ++mi) {
#pragma unroll
      for (int reg = 0; reg < 16; ++reg) {
        const int rl = mi * 32 + (reg & 3) + ((reg >> 2) << 3) + (hi << 2);
        const unsigned brow = (unsigned)(wr0 + rl);
        const unsigned bb = brow / 4000u;
        const unsigned tt = brow - bb * 4000u;
        const int sel = (bb != b0w);
        float rs = 0.f;
#pragma unroll
        for (int ni = 0; ni < 4; ++ni) {
          float s = acc[mi][ni][reg] + (sel ? av1[ni] : av0[ni]);
          rs += gvr[ni] * tanh_fast(s);
        }
        rs += __shfl_xor(rs, 1);
        rs += __shfl_xor(rs, 2);
        rs += __shfl_xor(rs, 4);
        rs += __shfl_xor(rs, 8);
        rs += __shfl_xor(rs, 16);
        if (ln31 == 0) e_out[((size_t)bb * H_ + h) * T_ + tt] = rs;
      }
    }
  }
}

// ---------------------------------------------------------------------------
__global__ __launch_bounds__(256) void k_msum(const float* __restrict__ e_in,
                                              float2* __restrict__ msum) {
  const int bh = blockIdx.x;
  const float* er = e_in + (size_t)bh * T_;
  __shared__ float red[256];
  const int tid = threadIdx.x;
  float m = -1e30f;
  for (int t = tid; t < T_; t += 256) m = fmaxf(m, er[t]);
  red[tid] = m;
  __syncthreads();
  for (int s = 128; s > 0; s >>= 1) {
    if (tid < s) red[tid] = fmaxf(red[tid], red[tid + s]);
    __syncthreads();
  }
  m = red[0];
  __syncthreads();
  float sum = 0.f;
  for (int t = tid; t < T_; t += 256) sum += __expf(er[t] - m);
  red[tid] = sum;
  __syncthreads();
  for (int s = 128; s > 0; s >>= 1) {
    if (tid < s) red[tid] += red[tid + s];
    __syncthreads();
  }
  if (tid == 0) msum[bh] = make_float2(m, 1.0f / red[0]);
}

// ---------------------------------------------------------------------------
__global__ __launch_bounds__(128) void k_ctx(const float* __restrict__ enc,
                                             const float* __restrict__ e_in,
                                             const float2* __restrict__ msum,
                                             float* __restrict__ wout,
                                             float* __restrict__ partial) {
  const int b = blockIdx.x, tc = blockIdx.y;
  const int t0 = tc * CH_;
  const int tid = threadIdx.x;
  __shared__ float wls[H_ * CH_];
  for (int i = tid; i < H_ * CH_; i += 128) {
    const int h = i / CH_, tt = i - h * CH_;
    const float2 ms = msum[b * H_ + h];
    const float w = __expf(e_in[((size_t)b * H_ + h) * T_ + t0 + tt] - ms.x) * ms.y;
    wls[i] = w;
    wout[((size_t)h * B_ + b) * T_ + t0 + tt] = w;
  }
  __syncthreads();
  float4 a0 = {0,0,0,0}, a1 = {0,0,0,0}, a2 = {0,0,0,0}, a3 = {0,0,0,0};
  const float4* enc4 = (const float4*)enc;
  const size_t ebase = ((size_t)b * T_ + t0) * 128 + tid;
#pragma unroll 8
  for (int tt = 0; tt < CH_; ++tt) {
    const float4 x = enc4[ebase + (size_t)tt * 128];
    const float w0 = wls[tt], w1 = wls[CH_ + tt], w2 = wls[2 * CH_ + tt], w3 = wls[3 * CH_ + tt];
    a0.x += w0 * x.x; a0.y += w0 * x.y; a0.z += w0 * x.z; a0.w += w0 * x.w;
    a1.x += w1 * x.x; a1.y += w1 * x.y; a1.z += w1 * x.z; a1.w += w1 * x.w;
    a2.x += w2 * x.x; a2.y += w2 * x.y; a2.z += w2 * x.z; a2.w += w2 * x.w;
    a3.x += w3 * x.x; a3.y += w3 * x.y; a3.z += w3 * x.z; a3.w += w3 * x.w;
  }
  float4* p4 = (float4*)partial;
  const size_t pbase = (((size_t)tc * B_ + b) * H_) * 128 + tid;
  p4[pbase] = a0;
  p4[pbase + 128] = a1;
  p4[pbase + 256] = a2;
  p4[pbase + 384] = a3;
}

// ---------------------------------------------------------------------------
__global__ __launch_bounds__(256) void k_out_part(const float* __restrict__ partial,
                                                  const float* __restrict__ Wo,
                                                  float* __restrict__ p2) {
  const int b = blockIdx.x;
  const int o = blockIdx.y * 256 + threadIdx.x;
  const int kc = blockIdx.z;
  __shared__ float cS[256];
  const int he0 = kc * 256;
  {
    float s = 0.f;
#pragma unroll
    for (int tc = 0; tc < TC_; ++tc)
      s += partial[((size_t)tc * B_ + b) * (H_ * E_) + he0 + threadIdx.x];
    cS[threadIdx.x] = s;
  }
  __syncthreads();
  float s = 0.f;
#pragma unroll 8
  for (int i = 0; i < 256; ++i) s += cS[i] * Wo[(size_t)(he0 + i) * O_ + o];
  p2[((size_t)kc * B_ + b) * O_ + o] = s;
}

__global__ __launch_bounds__(512) void k_out_fin(const float* __restrict__ p2,
                                                 const float* __restrict__ bo,
                                                 float* __restrict__ out) {
  const int b = blockIdx.x, o = threadIdx.x;
  float s = bo[o];
#pragma unroll
  for (int kc = 0; kc < 8; ++kc) s += p2[((size_t)kc * B_ + b) * O_ + o];
  out[b * O_ + o] = s;
}

// ---------------------------------------------------------------------------
extern "C" void kernel_launch(void* const* d_in, const int* in_sizes, int n_in,
                              void* d_out, int out_size, void* d_ws, size_t ws_size,
                              hipStream_t stream) {
  (void)in_sizes; (void)n_in; (void)out_size; (void)ws_size;
  const float* enc      = (const float*)d_in[0];
  // d_in[1] = enc_len : unused by the reference
  const float* dec_z    = (const float*)d_in[2];
  const float* att_prev = (const float*)d_in[3];
  const float* Wenc     = (const float*)d_in[4];
  const float* benc     = (const float*)d_in[5];
  const float* Wdec     = (const float*)d_in[6];
  const float* Watt     = (const float*)d_in[7];
  const float* conv_w   = (const float*)d_in[8];
  const float* gv       = (const float*)d_in[9];
  const float* Wo       = (const float*)d_in[10];
  const float* bo       = (const float*)d_in[11];

  float* out  = (float*)d_out;
  float* wout = out + B_ * O_;  // ws [H,B,T]

  char* wsb = (char*)d_ws;
  float*  e_buf   = (float*)(wsb);               // 1,024,000 B
  char*   convpad = wsb + 1024000;               // 8,192,000 B
  char*   wbs     = wsb + 9216000;               //   524,288 B
  char*   wattb   = wsb + 9740288;               //    16,384 B
  float*  addv4   = (float*)(wsb + 9756672);     //   131,072 B
  float2* msum    = (float2*)(wsb + 9887744);    //       512 B
  float*  partial = (float*)(wsb + 9888256);     // 6,553,600 B
  float*  p2      = (float*)(wsb + 16441856);    //   262,144 B

  hipLaunchKernelGGL(k_prep, dim3(257), dim3(256), 0, stream,
                     Wenc, Watt, dec_z, Wdec, benc, wbs, wattb, addv4);
  hipLaunchKernelGGL(k_conv, dim3(B_ * H_, 16), dim3(256), 0, stream, att_prev, conv_w, convpad);
  hipLaunchKernelGGL(k_fused_e_mfma, dim3(500), dim3(512), 0, stream,
                     enc, wbs, convpad, wattb, addv4, gv, e_buf);
  hipLaunchKernelGGL(k_msum, dim3(B_ * H_), dim3(256), 0, stream, e_buf, msum);
  hipLaunchKernelGGL(k_ctx, dim3(B_, TC_), dim3(128), 0, stream, enc, e_buf, msum, wout, partial);
  hipLaunchKernelGGL(k_out_part, dim3(B_, O_ / 256, 8), dim3(256), 0, stream, partial, Wo, p2);
  hipLaunchKernelGGL(k_out_fin, dim3(B_), dim3(512), 0, stream, p2, bo, out);
}

// Round 9
// 169.169 us; speedup vs baseline: 1.0817x; 1.0817x over previous
//
#include <hip/hip_runtime.h>
#include <hip/hip_bf16.h>

#define H_ 4
#define B_ 16
#define T_ 4000
#define E_ 512
#define D_ 512
#define A_ 128
#define C_ 10
#define K_ 101
#define O_ 512
#define TC_ 50
#define CH_ (T_ / TC_)   // 80

typedef __attribute__((ext_vector_type(16))) float f32x16;
typedef __attribute__((ext_vector_type(8)))  short short8;

#define MFMA32(a, b, c) __builtin_amdgcn_mfma_f32_32x32x16_bf16(a, b, c, 0, 0, 0)

#define GLL16(gp, lp) __builtin_amdgcn_global_load_lds( \
    (const __attribute__((address_space(1))) unsigned int*)(gp), \
    (__attribute__((address_space(3))) unsigned int*)(lp), 16, 0, 0)

static __device__ __forceinline__ unsigned short f2bf(float x) {
  unsigned u = __float_as_uint(x);
  unsigned r = (u + 0x7FFFu + ((u >> 16) & 1u)) >> 16;
  return (unsigned short)r;
}
static __device__ __forceinline__ unsigned pk2(float a, float b) {
  return (unsigned)f2bf(a) | ((unsigned)f2bf(b) << 16);
}
static __device__ __forceinline__ unsigned cvtpk(float lo, float hi) {
  unsigned r;
  asm("v_cvt_pk_bf16_f32 %0, %1, %2" : "=v"(r) : "v"(lo), "v"(hi));
  return r;
}
static __device__ __forceinline__ uint4 packbf8(float4 f0, float4 f1) {
  uint4 u;
  u.x = cvtpk(f0.x, f0.y); u.y = cvtpk(f0.z, f0.w);
  u.z = cvtpk(f1.x, f1.y); u.w = cvtpk(f1.z, f1.w);
  return u;
}
static __device__ __forceinline__ f32x16 zero16() {
  f32x16 z;
#pragma unroll
  for (int i = 0; i < 16; ++i) z[i] = 0.f;
  return z;
}
static __device__ __forceinline__ float tanh_fast(float x) {
  return 1.0f - 2.0f / (__expf(2.0f * x) + 1.0f);
}
// swizzled byte offset for 32-k-wide bf16 tiles packed as 2 rows per 128B line
static __device__ __forceinline__ int swz32(int r, int ksg) {
  return (r >> 1) * 128 + (((((r & 1) << 2) | ksg) ^ ((r >> 1) & 7)) << 4);
}

// ---------------------------------------------------------------------------
// k_prep: wbs = pre-swizzled bf16 Wenc [16 kt][512 n][32 k] (16KB per 256-col
// half per kt); wattb = pre-swizzled bf16 padded Watt; addv4 = 4-way split-K
// partials of benc + dec_z@Wdec, [p][b][h][a].
__global__ __launch_bounds__(256) void k_prep(const float* __restrict__ Wenc,
                                              const float* __restrict__ Watt,
                                              const float* __restrict__ dec_z,
                                              const float* __restrict__ Wdec,
                                              const float* __restrict__ benc,
                                              char* __restrict__ wbs,
                                              char* __restrict__ wattb,
                                              float* __restrict__ addv4) {
  const int bid = blockIdx.x;
  const int tid = threadIdx.x;
  if (bid < 128) {
    const int c = bid * 256 + tid;
    const int cc = c & 2047;
    const int kt = c >> 11;
    const int line = cc >> 3, sp = cc & 7;
    const int sraw = sp ^ (line & 7);
    const int n = line * 2 + (sraw >> 2);
    const int ksg = sraw & 3;
    const int h = n >> 7, a = n & 127;
    const int kb = kt * 32 + ksg * 8;
    uint4 u;
    u.x = pk2(Wenc[((size_t)h * E_ + kb + 0) * A_ + a], Wenc[((size_t)h * E_ + kb + 1) * A_ + a]);
    u.y = pk2(Wenc[((size_t)h * E_ + kb + 2) * A_ + a], Wenc[((size_t)h * E_ + kb + 3) * A_ + a]);
    u.z = pk2(Wenc[((size_t)h * E_ + kb + 4) * A_ + a], Wenc[((size_t)h * E_ + kb + 5) * A_ + a]);
    u.w = pk2(Wenc[((size_t)h * E_ + kb + 6) * A_ + a], Wenc[((size_t)h * E_ + kb + 7) * A_ + a]);
    ((uint4*)wbs)[c] = u;
  } else if (bid == 128) {
#pragma unroll
    for (int q = 0; q < 4; ++q) {
      const int cw = q * 256 + tid;
      const int h = cw >> 8, cc = cw & 255;
      const int line = cc >> 3, sp = cc & 7;
      const int sraw = sp ^ (line & 7);
      const int a = line * 4 + (sraw >> 1);
      const int s = sraw & 1;
      unsigned short v[8];
#pragma unroll
      for (int j = 0; j < 8; ++j) {
        const int k = s * 8 + j;
        v[j] = (k < C_) ? f2bf(Watt[((size_t)h * C_ + k) * A_ + a]) : (unsigned short)0;
      }
      uint4 u;
      u.x = (unsigned)v[0] | ((unsigned)v[1] << 16);
      u.y = (unsigned)v[2] | ((unsigned)v[3] << 16);
      u.z = (unsigned)v[4] | ((unsigned)v[5] << 16);
      u.w = (unsigned)v[6] | ((unsigned)v[7] << 16);
      ((uint4*)wattb)[cw] = u;
    }
  } else {
    const int idx = bid - 129;
    const int b = idx >> 3, h = (idx >> 1) & 3, ks = idx & 1;
    const int a = tid & 127, kh = tid >> 7;
    const int p = ks * 2 + kh;
    const int d0 = p * 128;
    const float* z = dec_z + (size_t)b * D_ + d0;
    const float* w = Wdec + ((size_t)h * D_ + d0) * A_ + a;
    float s = (p == 0) ? benc[h * A_ + a] : 0.f;
#pragma unroll 8
    for (int d = 0; d < 128; ++d) s += z[d] * w[(size_t)d * A_];
    addv4[(((size_t)p * B_ + b) * H_ + h) * A_ + a] = s;
  }
}

// ---------------------------------------------------------------------------
__global__ __launch_bounds__(256) void k_conv(const float* __restrict__ att_prev,
                                              const float* __restrict__ conv_w,
                                              char* __restrict__ convpad) {
  const int bh = blockIdx.x;
  const int b = bh / H_, h = bh % H_;
  const int t0 = blockIdx.y * 256;
  __shared__ float ap[256 + K_ - 1 + 3];
  __shared__ float cw[C_ * K_];
  const float* src = att_prev + ((size_t)h * B_ + b) * T_;
  for (int i = threadIdx.x; i < 256 + K_ - 1; i += 256) {
    int tt = t0 - (K_ / 2) + i;
    ap[i] = (tt >= 0 && tt < T_) ? src[tt] : 0.f;
  }
  for (int i = threadIdx.x; i < C_ * K_; i += 256) cw[i] = conv_w[(size_t)h * C_ * K_ + i];
  __syncthreads();
  const int t = t0 + threadIdx.x;
  if (t < T_) {
    float s[C_];
#pragma unroll
    for (int c = 0; c < C_; ++c) s[c] = 0.f;
    for (int k = 0; k < K_; ++k) {
      float apv = ap[threadIdx.x + k];
#pragma unroll
      for (int c = 0; c < C_; ++c) s[c] += cw[c * K_ + k] * apv;
    }
    uint4 u0, u1;
    u0.x = pk2(s[0], s[1]); u0.y = pk2(s[2], s[3]);
    u0.z = pk2(s[4], s[5]); u0.w = pk2(s[6], s[7]);
    u1.x = pk2(s[8], s[9]); u1.y = 0u; u1.z = 0u; u1.w = 0u;
    char* dst = convpad + (size_t)(b * T_ + t) * 128 + h * 32;
    *(uint4*)dst = u0;
    *(uint4*)(dst + 16) = u1;
  }
}

// ---------------------------------------------------------------------------
// Fused MFMA — m201-style phase schedule.
// Block 256 rows x 256 cols (2 heads), 8 waves (wm 2 x wn 4), per-wave
// 128x64 -> acc[4][2] = 128 AGPRs. BK=32, 16 K-tiles, tri-buffered LDS
// (3 x {A 16KB + B 16KB} = 96KB) with prefetch distance 2 tiles.
// Per tile 2 phases; each phase: 6 ds_read -> stage-issue -> barrier ->
// lgkmcnt(0) -> setprio(1) 8 MFMA setprio(0). vmcnt(6) ONCE per tile
// (never 0 until tile 14). A reg-staged (fp32->cvt_pk->swizzled ds_write,
// ping-pong reg sets); B via global_load_lds from pre-swizzled wbs.
__global__ __launch_bounds__(512, 2) void k_fused_e_mfma(
    const float* __restrict__ enc,
    const char*  __restrict__ wbs,
    const char*  __restrict__ convpad,
    const char*  __restrict__ wattb,
    const float* __restrict__ addv4,
    const float* __restrict__ gv,
    float* __restrict__ e_out) {
  __shared__ char smem[102400];  // 3 x 32KB bufs + 4KB P-exchange
  const int tid = threadIdx.x;
  const int wv = tid >> 6;
  const int wm = wv >> 2;        // row-half: rows wm*128..+127
  const int wn = wv & 3;         // col-quarter: cols wn*64..+63
  const int lane = tid & 63, ln31 = lane & 31, hi = lane >> 5;
  const int m0 = blockIdx.x * 256;
  const int nb = blockIdx.y;     // heads {2nb, 2nb+1}
  const int hloc = wn >> 1, h = nb * 2 + hloc;

  f32x16 acc[4][2];
#pragma unroll
  for (int i = 0; i < 4; ++i)
#pragma unroll
    for (int j = 0; j < 2; ++j) acc[i][j] = zero16();

  // ds_read fragment offsets (kc=0 and ^32 for kc=1)
  const int A0o = swz32(wm * 128 +  0 + ln31, hi);
  const int A1o = swz32(wm * 128 + 32 + ln31, hi);
  const int A2o = swz32(wm * 128 + 64 + ln31, hi);
  const int A3o = swz32(wm * 128 + 96 + ln31, hi);
  const int B0o = 16384 + swz32(wn * 64 + ln31, hi);
  const int B1o = 16384 + swz32(wn * 64 + 32 + ln31, hi);
  const int A0x = A0o ^ 32, A1x = A1o ^ 32, A2x = A2o ^ 32, A3x = A3o ^ 32;
  const int B0x = B0o ^ 32, B1x = B1o ^ 32;

  // A staging geometry: thread stages rows (tid>>2) and (tid>>2)+128, ksg=tid&3
  const int arow = tid >> 2, aksg = tid & 3;
  const float* encA0 = enc + (size_t)(m0 + arow) * E_ + aksg * 8;
  const float* encA1 = encA0 + (size_t)128 * E_;
  const int wrA0 = swz32(arow, aksg);
  const int wrA1 = swz32(arow + 128, aksg);
  const char* wbsrc = wbs + nb * 16384 + wv * 1024 + lane * 16;

  float4 rX0, rX1, rX2, rX3, rY0, rY1, rY2, rY3;
  short8 a0f, a1f, a2f, a3f, b0f, b1f;
  short8 cv0, cv1, cv2, cv3, wt0, wt1;
  float av00 = 0.f, av01 = 0.f, av10 = 0.f, av11 = 0.f, gv0 = 0.f, gv1 = 0.f;

#define SBAR __builtin_amdgcn_sched_barrier(0)

#define ALOADX(KT) do { \
    rX0 = *(const float4*)(encA0 + (KT) * 32); \
    rX1 = *(const float4*)(encA0 + (KT) * 32 + 4); \
    rX2 = *(const float4*)(encA1 + (KT) * 32); \
    rX3 = *(const float4*)(encA1 + (KT) * 32 + 4); \
  } while (0)
#define ALOADY(KT) do { \
    rY0 = *(const float4*)(encA0 + (KT) * 32); \
    rY1 = *(const float4*)(encA0 + (KT) * 32 + 4); \
    rY2 = *(const float4*)(encA1 + (KT) * 32); \
    rY3 = *(const float4*)(encA1 + (KT) * 32 + 4); \
  } while (0)
#define AWRITEX(BUF) do { \
    *(uint4*)(smem + (BUF) + wrA0) = packbf8(rX0, rX1); \
    *(uint4*)(smem + (BUF) + wrA1) = packbf8(rX2, rX3); \
  } while (0)
#define AWRITEY(BUF) do { \
    *(uint4*)(smem + (BUF) + wrA0) = packbf8(rY0, rY1); \
    *(uint4*)(smem + (BUF) + wrA1) = packbf8(rY2, rY3); \
  } while (0)
#define BGLL(BUFN, KT) do { \
    GLL16(wbsrc + (size_t)(KT) * 32768, smem + (BUFN) + 16384 + wv * 1024); \
    GLL16(wbsrc + (size_t)(KT) * 32768 + 8192, smem + (BUFN) + 24576 + wv * 1024); \
  } while (0)
#define DSR(BUF, O0, O1, O2, O3, O4, O5) do { \
    a0f = *(const short8*)(smem + (BUF) + (O0)); \
    a1f = *(const short8*)(smem + (BUF) + (O1)); \
    a2f = *(const short8*)(smem + (BUF) + (O2)); \
    a3f = *(const short8*)(smem + (BUF) + (O3)); \
    b0f = *(const short8*)(smem + (BUF) + (O4)); \
    b1f = *(const short8*)(smem + (BUF) + (O5)); \
  } while (0)
#define MFMA8 do { \
    acc[0][0] = MFMA32(a0f, b0f, acc[0][0]); \
    acc[1][0] = MFMA32(a1f, b0f, acc[1][0]); \
    acc[2][0] = MFMA32(a2f, b0f, acc[2][0]); \
    acc[3][0] = MFMA32(a3f, b0f, acc[3][0]); \
    acc[0][1] = MFMA32(a0f, b1f, acc[0][1]); \
    acc[1][1] = MFMA32(a1f, b1f, acc[1][1]); \
    acc[2][1] = MFMA32(a2f, b1f, acc[2][1]); \
    acc[3][1] = MFMA32(a3f, b1f, acc[3][1]); \
  } while (0)

#define PH0(BUF, LOADSTMT) do { \
    DSR(BUF, A0o, A1o, A2o, A3o, B0o, B1o); \
    LOADSTMT; \
    SBAR; \
    __builtin_amdgcn_s_barrier(); \
    asm volatile("s_waitcnt lgkmcnt(0)" ::: "memory"); \
    SBAR; \
    __builtin_amdgcn_s_setprio(1); \
    MFMA8; \
    __builtin_amdgcn_s_setprio(0); \
    SBAR; \
  } while (0)
#define PH1(BUF, GLSTMT, VMS, WRSTMT) do { \
    DSR(BUF, A0x, A1x, A2x, A3x, B0x, B1x); \
    GLSTMT; \
    SBAR; \
    asm volatile("s_waitcnt " VMS ::: "memory"); \
    SBAR; \
    WRSTMT; \
    asm volatile("s_waitcnt lgkmcnt(0)" ::: "memory"); \
    SBAR; \
    __builtin_amdgcn_s_barrier(); \
    __builtin_amdgcn_s_setprio(1); \
    MFMA8; \
    __builtin_amdgcn_s_setprio(0); \
    SBAR; \
  } while (0)
#define NOP ((void)0)
#define TILEE(KT2, BUF, BUFN, WBUF) \
    PH0(BUF, ALOADX(KT2)); \
    PH1(BUF, BGLL(BUFN, KT2), "vmcnt(6)", AWRITEY(WBUF))
#define TILEO(KT2, BUF, BUFN, WBUF) \
    PH0(BUF, ALOADY(KT2)); \
    PH1(BUF, BGLL(BUFN, KT2), "vmcnt(6)", AWRITEX(WBUF))

  // ---- prologue: stage tiles 0 (->buf0) and 1 (->buf1)
  ALOADX(0);
  SBAR;
  ALOADY(1);
  SBAR;
  BGLL(0, 0);
  SBAR;
  BGLL(32768, 1);
  SBAR;
  asm volatile("s_waitcnt vmcnt(4)" ::: "memory");  // rX,rY arrived
  SBAR;
  AWRITEX(0);                                        // A0 -> buf0
  asm volatile("s_waitcnt vmcnt(2) lgkmcnt(0)" ::: "memory");  // B0 arrived
  SBAR;
  __builtin_amdgcn_s_barrier();

  // ---- 16 tiles, buf = t%3, prefetch t+2, reg-set = t&1
  TILEE(2, 0, 65536, 32768);        // t=0
  TILEO(3, 32768, 0, 65536);        // t=1
  TILEE(4, 65536, 32768, 0);        // t=2
  TILEO(5, 0, 65536, 32768);        // t=3
  TILEE(6, 32768, 0, 65536);        // t=4
  TILEO(7, 65536, 32768, 0);        // t=5
  TILEE(8, 0, 65536, 32768);        // t=6
  TILEO(9, 32768, 0, 65536);        // t=7
  TILEE(10, 65536, 32768, 0);       // t=8
  TILEO(11, 0, 65536, 32768);       // t=9
  TILEE(12, 32768, 0, 65536);       // t=10
  TILEO(13, 65536, 32768, 0);       // t=11
  TILEE(14, 0, 65536, 32768);       // t=12
  TILEO(15, 32768, 0, 65536);       // t=13
  // t=14 (buf2): no prefetch; drain; write A15 (set Y) -> buf0
  PH0(65536, NOP);
  PH1(65536, NOP, "vmcnt(0)", AWRITEY(0));
  // t=15 (buf0): conv/Watt frag loads at p0, addv/gv at p1
  PH0(0,
      do {
        cv0 = *(const short8*)(convpad + (size_t)(m0 + wm * 128 +  0 + ln31) * 128 + h * 32 + hi * 16);
        cv1 = *(const short8*)(convpad + (size_t)(m0 + wm * 128 + 32 + ln31) * 128 + h * 32 + hi * 16);
        cv2 = *(const short8*)(convpad + (size_t)(m0 + wm * 128 + 64 + ln31) * 128 + h * 32 + hi * 16);
        cv3 = *(const short8*)(convpad + (size_t)(m0 + wm * 128 + 96 + ln31) * 128 + h * 32 + hi * 16);
        const int ar0 = (wn & 1) * 64 + ln31;
        const int ar1 = ar0 + 32;
        wt0 = *(const short8*)(wattb + h * 4096 + (ar0 >> 2) * 128 +
                               (((((ar0 & 3) << 1) | hi) ^ ((ar0 >> 2) & 7)) << 4));
        wt1 = *(const short8*)(wattb + h * 4096 + (ar1 >> 2) * 128 +
                               (((((ar1 & 3) << 1) | hi) ^ ((ar1 >> 2) & 7)) << 4));
      } while (0));
  {
    const int wr0 = m0 + wm * 128;
    const unsigned b0w = (unsigned)wr0 / 4000u;
    const unsigned b1w = (unsigned)(wr0 + 127) / 4000u;
    PH1(0,
        do {
          const int a0c = (wn & 1) * 64 + ln31;
          const int a1c = a0c + 32;
          const int i00 = (int)b0w * 512 + h * 128 + a0c;
          const int i01 = (int)b0w * 512 + h * 128 + a1c;
          const int i10 = (int)b1w * 512 + h * 128 + a0c;
          const int i11 = (int)b1w * 512 + h * 128 + a1c;
          av00 = addv4[i00] + addv4[8192 + i00] + addv4[16384 + i00] + addv4[24576 + i00];
          av01 = addv4[i01] + addv4[8192 + i01] + addv4[16384 + i01] + addv4[24576 + i01];
          av10 = addv4[i10] + addv4[8192 + i10] + addv4[16384 + i10] + addv4[24576 + i10];
          av11 = addv4[i11] + addv4[8192 + i11] + addv4[16384 + i11] + addv4[24576 + i11];
          gv0 = gv[h * 128 + a0c];
          gv1 = gv[h * 128 + a1c];
        } while (0),
        "vmcnt(0)", NOP);

    // ---- conv MFMA (K=16)
    asm volatile("s_waitcnt vmcnt(0) lgkmcnt(0)" ::: "memory");
    SBAR;
    acc[0][0] = MFMA32(cv0, wt0, acc[0][0]);
    acc[1][0] = MFMA32(cv1, wt0, acc[1][0]);
    acc[2][0] = MFMA32(cv2, wt0, acc[2][0]);
    acc[3][0] = MFMA32(cv3, wt0, acc[3][0]);
    acc[0][1] = MFMA32(cv0, wt1, acc[0][1]);
    acc[1][1] = MFMA32(cv1, wt1, acc[1][1]);
    acc[2][1] = MFMA32(cv2, wt1, acc[2][1]);
    acc[3][1] = MFMA32(cv3, wt1, acc[3][1]);

    // ---- epilogue: tanh + gv-dot + 32-lane reduce -> per-wave partials
    float* Pb = (float*)(smem + 98304);
#pragma unroll
    for (int mi = 0; mi < 4; ++mi) {
#pragma unroll
      for (int reg = 0; reg < 16; ++reg) {
        const int crow = (reg & 3) + ((reg >> 2) << 3) + (hi << 2);
        const int rloc = mi * 32 + crow;                 // 0..127 within wave
        const unsigned brow = (unsigned)(wr0 + rloc);
        const unsigned bb = brow / 4000u;
        const int sel = (bb != b0w);
        float rs = gv0 * tanh_fast(acc[mi][0][reg] + (sel ? av10 : av00))
                 + gv1 * tanh_fast(acc[mi][1][reg] + (sel ? av11 : av01));
        rs += __shfl_xor(rs, 1);
        rs += __shfl_xor(rs, 2);
        rs += __shfl_xor(rs, 4);
        rs += __shfl_xor(rs, 8);
        rs += __shfl_xor(rs, 16);
        if (ln31 == 0) Pb[wv * 128 + rloc] = rs;
      }
    }
  }
  __syncthreads();

  // cross-wave a-half sum + store e: 512 outputs = 2 heads x 256 rows
  {
    const float* Pb = (const float*)(smem + 98304);
    const int hl = tid >> 8, r = tid & 255;
    const int wmf = r >> 7, rloc = r & 127;
    const float ev = Pb[(wmf * 4 + hl * 2) * 128 + rloc] +
                     Pb[(wmf * 4 + hl * 2 + 1) * 128 + rloc];
    const unsigned brow = (unsigned)(m0 + r);
    const unsigned bb = brow / 4000u;
    const unsigned tt = brow - bb * 4000u;
    e_out[((size_t)bb * H_ + nb * 2 + hl) * T_ + tt] = ev;
  }
#undef SBAR
#undef ALOADX
#undef ALOADY
#undef AWRITEX
#undef AWRITEY
#undef BGLL
#undef DSR
#undef MFMA8
#undef PH0
#undef PH1
#undef NOP
#undef TILEE
#undef TILEO
}

// ---------------------------------------------------------------------------
__global__ __launch_bounds__(256) void k_msum(const float* __restrict__ e_in,
                                              float2* __restrict__ msum) {
  const int bh = blockIdx.x;
  const float* er = e_in + (size_t)bh * T_;
  __shared__ float red[256];
  const int tid = threadIdx.x;
  float m = -1e30f;
  for (int t = tid; t < T_; t += 256) m = fmaxf(m, er[t]);
  red[tid] = m;
  __syncthreads();
  for (int s = 128; s > 0; s >>= 1) {
    if (tid < s) red[tid] = fmaxf(red[tid], red[tid + s]);
    __syncthreads();
  }
  m = red[0];
  __syncthreads();
  float sum = 0.f;
  for (int t = tid; t < T_; t += 256) sum += __expf(er[t] - m);
  red[tid] = sum;
  __syncthreads();
  for (int s = 128; s > 0; s >>= 1) {
    if (tid < s) red[tid] += red[tid + s];
    __syncthreads();
  }
  if (tid == 0) msum[bh] = make_float2(m, 1.0f / red[0]);
}

// ---------------------------------------------------------------------------
__global__ __launch_bounds__(128) void k_ctx(const float* __restrict__ enc,
                                             const float* __restrict__ e_in,
                                             const float2* __restrict__ msum,
                                             float* __restrict__ wout,
                                             float* __restrict__ partial) {
  const int b = blockIdx.x, tc = blockIdx.y;
  const int t0 = tc * CH_;
  const int tid = threadIdx.x;
  __shared__ float wls[H_ * CH_];
  for (int i = tid; i < H_ * CH_; i += 128) {
    const int h = i / CH_, tt = i - h * CH_;
    const float2 ms = msum[b * H_ + h];
    const float w = __expf(e_in[((size_t)b * H_ + h) * T_ + t0 + tt] - ms.x) * ms.y;
    wls[i] = w;
    wout[((size_t)h * B_ + b) * T_ + t0 + tt] = w;
  }
  __syncthreads();
  float4 a0 = {0,0,0,0}, a1 = {0,0,0,0}, a2 = {0,0,0,0}, a3 = {0,0,0,0};
  const float4* enc4 = (const float4*)enc;
  const size_t ebase = ((size_t)b * T_ + t0) * 128 + tid;
#pragma unroll 8
  for (int tt = 0; tt < CH_; ++tt) {
    const float4 x = enc4[ebase + (size_t)tt * 128];
    const float w0 = wls[tt], w1 = wls[CH_ + tt], w2 = wls[2 * CH_ + tt], w3 = wls[3 * CH_ + tt];
    a0.x += w0 * x.x; a0.y += w0 * x.y; a0.z += w0 * x.z; a0.w += w0 * x.w;
    a1.x += w1 * x.x; a1.y += w1 * x.y; a1.z += w1 * x.z; a1.w += w1 * x.w;
    a2.x += w2 * x.x; a2.y += w2 * x.y; a2.z += w2 * x.z; a2.w += w2 * x.w;
    a3.x += w3 * x.x; a3.y += w3 * x.y; a3.z += w3 * x.z; a3.w += w3 * x.w;
  }
  float4* p4 = (float4*)partial;
  const size_t pbase = (((size_t)tc * B_ + b) * H_) * 128 + tid;
  p4[pbase] = a0;
  p4[pbase + 128] = a1;
  p4[pbase + 256] = a2;
  p4[pbase + 384] = a3;
}

// ---------------------------------------------------------------------------
__global__ __launch_bounds__(256) void k_out_part(const float* __restrict__ partial,
                                                  const float* __restrict__ Wo,
                                                  float* __restrict__ p2) {
  const int b = blockIdx.x;
  const int o = blockIdx.y * 256 + threadIdx.x;
  const int kc = blockIdx.z;
  __shared__ float cS[256];
  const int he0 = kc * 256;
  {
    float s = 0.f;
#pragma unroll
    for (int tc = 0; tc < TC_; ++tc)
      s += partial[((size_t)tc * B_ + b) * (H_ * E_) + he0 + threadIdx.x];
    cS[threadIdx.x] = s;
  }
  __syncthreads();
  float s = 0.f;
#pragma unroll 8
  for (int i = 0; i < 256; ++i) s += cS[i] * Wo[(size_t)(he0 + i) * O_ + o];
  p2[((size_t)kc * B_ + b) * O_ + o] = s;
}

__global__ __launch_bounds__(512) void k_out_fin(const float* __restrict__ p2,
                                                 const float* __restrict__ bo,
                                                 float* __restrict__ out) {
  const int b = blockIdx.x, o = threadIdx.x;
  float s = bo[o];
#pragma unroll
  for (int kc = 0; kc < 8; ++kc) s += p2[((size_t)kc * B_ + b) * O_ + o];
  out[b * O_ + o] = s;
}

// ---------------------------------------------------------------------------
extern "C" void kernel_launch(void* const* d_in, const int* in_sizes, int n_in,
                              void* d_out, int out_size, void* d_ws, size_t ws_size,
                              hipStream_t stream) {
  (void)in_sizes; (void)n_in; (void)out_size; (void)ws_size;
  const float* enc      = (const float*)d_in[0];
  // d_in[1] = enc_len : unused by the reference
  const float* dec_z    = (const float*)d_in[2];
  const float* att_prev = (const float*)d_in[3];
  const float* Wenc     = (const float*)d_in[4];
  const float* benc     = (const float*)d_in[5];
  const float* Wdec     = (const float*)d_in[6];
  const float* Watt     = (const float*)d_in[7];
  const float* conv_w   = (const float*)d_in[8];
  const float* gv       = (const float*)d_in[9];
  const float* Wo       = (const float*)d_in[10];
  const float* bo       = (const float*)d_in[11];

  float* out  = (float*)d_out;
  float* wout = out + B_ * O_;  // ws [H,B,T]

  char* wsb = (char*)d_ws;
  float*  e_buf   = (float*)(wsb);               // 1,024,000 B
  char*   convpad = wsb + 1024000;               // 8,192,000 B
  char*   wbs     = wsb + 9216000;               //   524,288 B
  char*   wattb   = wsb + 9740288;               //    16,384 B
  float*  addv4   = (float*)(wsb + 9756672);     //   131,072 B
  float2* msum    = (float2*)(wsb + 9887744);    //       512 B
  float*  partial = (float*)(wsb + 9888256);     // 6,553,600 B
  float*  p2      = (float*)(wsb + 16441856);    //   262,144 B

  hipLaunchKernelGGL(k_prep, dim3(257), dim3(256), 0, stream,
                     Wenc, Watt, dec_z, Wdec, benc, wbs, wattb, addv4);
  hipLaunchKernelGGL(k_conv, dim3(B_ * H_, 16), dim3(256), 0, stream, att_prev, conv_w, convpad);
  hipLaunchKernelGGL(k_fused_e_mfma, dim3(250, 2), dim3(512), 0, stream,
                     enc, wbs, convpad, wattb, addv4, gv, e_buf);
  hipLaunchKernelGGL(k_msum, dim3(B_ * H_), dim3(256), 0, stream, e_buf, msum);
  hipLaunchKernelGGL(k_ctx, dim3(B_, TC_), dim3(128), 0, stream, enc, e_buf, msum, wout, partial);
  hipLaunchKernelGGL(k_out_part, dim3(B_, O_ / 256, 8), dim3(256), 0, stream, partial, Wo, p2);
  hipLaunchKernelGGL(k_out_fin, dim3(B_), dim3(512), 0, stream, p2, bo, out);
}

// Round 10
// 166.417 us; speedup vs baseline: 1.0996x; 1.0165x over previous
//
#include <hip/hip_runtime.h>
#include <hip/hip_bf16.h>

#define H_ 4
#define B_ 16
#define T_ 4000
#define E_ 512
#define D_ 512
#define A_ 128
#define C_ 10
#define K_ 101
#define O_ 512
#define TC_ 50
#define CH_ (T_ / TC_)   // 80

typedef __attribute__((ext_vector_type(4))) float f32x4;
typedef __attribute__((ext_vector_type(8)))  short short8;

#define MFMA16(a, b, c) __builtin_amdgcn_mfma_f32_16x16x32_bf16(a, b, c, 0, 0, 0)

#define GLL16(gp, lp) __builtin_amdgcn_global_load_lds( \
    (const __attribute__((address_space(1))) unsigned int*)(gp), \
    (__attribute__((address_space(3))) unsigned int*)(lp), 16, 0, 0)

static __device__ __forceinline__ unsigned short f2bf(float x) {
  unsigned u = __float_as_uint(x);
  unsigned r = (u + 0x7FFFu + ((u >> 16) & 1u)) >> 16;
  return (unsigned short)r;
}
static __device__ __forceinline__ unsigned pk2(float a, float b) {
  return (unsigned)f2bf(a) | ((unsigned)f2bf(b) << 16);
}
static __device__ __forceinline__ unsigned cvtpk(float lo, float hi) {
  unsigned r;
  asm("v_cvt_pk_bf16_f32 %0, %1, %2" : "=v"(r) : "v"(lo), "v"(hi));
  return r;
}
static __device__ __forceinline__ uint4 packbf8(float4 f0, float4 f1) {
  uint4 u;
  u.x = cvtpk(f0.x, f0.y); u.y = cvtpk(f0.z, f0.w);
  u.z = cvtpk(f1.x, f1.y); u.w = cvtpk(f1.z, f1.w);
  return u;
}
static __device__ __forceinline__ float tanh_fast(float x) {
  return 1.0f - 2.0f / (__expf(2.0f * x) + 1.0f);
}
// data-permutation swizzle for [row][32k] bf16 tiles (4 chunks of 16B/row):
// image chunk (row,c) holds data k-block (c ^ sw(row)), sw = (r&3)^((r>>2)&3).
static __device__ __forceinline__ int swz(int r) {
  return (r & 3) ^ ((r >> 2) & 3);
}

// ---------------------------------------------------------------------------
// k_prep: wbs2 [h][kt][row-image 8KB] = pre-swizzled bf16 Wenc^T tiles
// (col-major: image row = a-col, 32 k per row); wattb2 [h][a][16k] plain bf16;
// addv4 = 4-way split-K partials of benc + dec_z@Wdec, [p][b][h][a].
__global__ __launch_bounds__(256) void k_prep(const float* __restrict__ Wenc,
                                              const float* __restrict__ Watt,
                                              const float* __restrict__ dec_z,
                                              const float* __restrict__ Wdec,
                                              const float* __restrict__ benc,
                                              char* __restrict__ wbs2,
                                              char* __restrict__ wattb2,
                                              float* __restrict__ addv4) {
  const int bid = blockIdx.x;
  const int tid = threadIdx.x;
  if (bid < 128) {
    const int c = bid * 256 + tid;       // 16B chunk: [h][kt][col][cc]
    const int h = c >> 13;
    const int r = c & 8191;
    const int kt = r >> 9;
    const int ci = r & 511;
    const int col = ci >> 2, cc = ci & 3;
    const int kk = kt * 32 + ((cc ^ swz(col)) & 3) * 8;
    const float* w = Wenc + ((size_t)h * E_ + kk) * A_ + col;
    uint4 u;
    u.x = pk2(w[0], w[A_]);
    u.y = pk2(w[2 * A_], w[3 * A_]);
    u.z = pk2(w[4 * A_], w[5 * A_]);
    u.w = pk2(w[6 * A_], w[7 * A_]);
    ((uint4*)wbs2)[c] = u;
  } else if (bid == 128) {
#pragma unroll
    for (int q = 0; q < 4; ++q) {
      const int cw = q * 256 + tid;      // [h][col][half] 16B chunks
      const int h = cw >> 8;
      const int rr = cw & 255;
      const int col = rr >> 1, half = rr & 1;
      unsigned short v[8];
#pragma unroll
      for (int j = 0; j < 8; ++j) {
        const int k = half * 8 + j;
        v[j] = (k < C_) ? f2bf(Watt[((size_t)h * C_ + k) * A_ + col]) : (unsigned short)0;
      }
      uint4 u;
      u.x = (unsigned)v[0] | ((unsigned)v[1] << 16);
      u.y = (unsigned)v[2] | ((unsigned)v[3] << 16);
      u.z = (unsigned)v[4] | ((unsigned)v[5] << 16);
      u.w = (unsigned)v[6] | ((unsigned)v[7] << 16);
      ((uint4*)wattb2)[cw] = u;
    }
  } else {
    const int idx = bid - 129;
    const int b = idx >> 3, h = (idx >> 1) & 3, ks = idx & 1;
    const int a = tid & 127, kh = tid >> 7;
    const int p = ks * 2 + kh;
    const int d0 = p * 128;
    const float* z = dec_z + (size_t)b * D_ + d0;
    const float* w = Wdec + ((size_t)h * D_ + d0) * A_ + a;
    float s = (p == 0) ? benc[h * A_ + a] : 0.f;
#pragma unroll 8
    for (int d = 0; d < 128; ++d) s += z[d] * w[(size_t)d * A_];
    addv4[(((size_t)p * B_ + b) * H_ + h) * A_ + a] = s;
  }
}

// ---------------------------------------------------------------------------
__global__ __launch_bounds__(256) void k_conv(const float* __restrict__ att_prev,
                                              const float* __restrict__ conv_w,
                                              char* __restrict__ convpad) {
  const int bh = blockIdx.x;
  const int b = bh / H_, h = bh % H_;
  const int t0 = blockIdx.y * 256;
  __shared__ float ap[256 + K_ - 1 + 3];
  __shared__ float cw[C_ * K_];
  const float* src = att_prev + ((size_t)h * B_ + b) * T_;
  for (int i = threadIdx.x; i < 256 + K_ - 1; i += 256) {
    int tt = t0 - (K_ / 2) + i;
    ap[i] = (tt >= 0 && tt < T_) ? src[tt] : 0.f;
  }
  for (int i = threadIdx.x; i < C_ * K_; i += 256) cw[i] = conv_w[(size_t)h * C_ * K_ + i];
  __syncthreads();
  const int t = t0 + threadIdx.x;
  if (t < T_) {
    float s[C_];
#pragma unroll
    for (int c = 0; c < C_; ++c) s[c] = 0.f;
    for (int k = 0; k < K_; ++k) {
      float apv = ap[threadIdx.x + k];
#pragma unroll
      for (int c = 0; c < C_; ++c) s[c] += cw[c * K_ + k] * apv;
    }
    uint4 u0, u1;
    u0.x = pk2(s[0], s[1]); u0.y = pk2(s[2], s[3]);
    u0.z = pk2(s[4], s[5]); u0.w = pk2(s[6], s[7]);
    u1.x = pk2(s[8], s[9]); u1.y = 0u; u1.z = 0u; u1.w = 0u;
    char* dst = convpad + (size_t)(b * T_ + t) * 128 + h * 32;
    *(uint4*)dst = u0;
    *(uint4*)(dst + 16) = u1;
  }
}

// ---------------------------------------------------------------------------
// Fused MFMA — m97-faithful structure.
// Block = 1 head x 128 rows, 256 threads (4 waves, 2x2 of 64x64). Per-wave
// acc[4][4] of 16x16x32 frags = 64 AGPRs -> ~3 blocks/CU co-resident (the
// m114 mechanism that absorbs the per-kt barrier drain; rounds 2-6 had
// 1 block/CU and flatlined at 87us). BK=32, 16 K-steps, double-buffered
// 32KB LDS, plain __syncthreads per step (m97 pattern).
// A: reg-staged fp32->cvt_pk->linear ds_write (bank-uniform; swizzle is a
// DATA permutation applied at load). B: 2x GLL16/thread from pre-swizzled
// image wbs2. Conv folded as one K=32 MFMA step (k>=16 lanes zeroed).
__global__ __launch_bounds__(256, 3) void k_fused_e_mfma(
    const float* __restrict__ enc,
    const char*  __restrict__ wbs2,
    const char*  __restrict__ convpad,
    const char*  __restrict__ wattb2,
    const float* __restrict__ addv4,
    const float* __restrict__ gv,
    float* __restrict__ e_out) {
  __shared__ char smem[32768];   // A: 0,8192 ; B: 16384,24576
  const int tid = threadIdx.x;
  const int wv = tid >> 6, wm = wv >> 1, wn = wv & 1;
  const int lane = tid & 63, l15 = lane & 15, lg = lane >> 4;
  const int h = blockIdx.x;
  const int m0 = blockIdx.y * 128;

  f32x4 acc[4][4];
#pragma unroll
  for (int i = 0; i < 4; ++i)
#pragma unroll
    for (int j = 0; j < 4; ++j) acc[i][j] = (f32x4){0.f, 0.f, 0.f, 0.f};

  // ---- A staging geometry: thread t stages rows (t>>2) and (t>>2)+64,
  // chunk (t&3). Data k-block = (chunk ^ swz(row)); same for both rows
  // (row+64 leaves bits 0..3 unchanged).
  const int arow = tid >> 2, ac = tid & 3;
  const int ks = ((ac ^ swz(arow)) & 3) * 8;
  const float* eR0 = enc + (size_t)(m0 + arow) * E_ + ks;
  const float* eR1 = eR0 + (size_t)64 * E_;
  const int wOff0 = arow * 64 + ac * 16;
  const int wOff1 = (arow + 64) * 64 + ac * 16;

  // ---- B staging: linear image copy, 2 GLL16/thread
  const char* bsrc = wbs2 + (size_t)h * 131072 + wv * 1024 + lane * 16;

  // ---- fragment read offsets (within an 8KB tile)
  int aOff[4], bOff[4];
#pragma unroll
  for (int q = 0; q < 4; ++q) {
    const int row = wm * 64 + q * 16 + l15;
    aOff[q] = row * 64 + (((lg ^ swz(row)) & 3) << 4);
    const int col = wn * 64 + q * 16 + l15;
    bOff[q] = col * 64 + (((lg ^ swz(col)) & 3) << 4);
  }

  // ---- prologue: stage kt0 into buf0
  {
    float4 a00 = *(const float4*)eR0;
    float4 a01 = *(const float4*)(eR0 + 4);
    float4 a10 = *(const float4*)eR1;
    float4 a11 = *(const float4*)(eR1 + 4);
    GLL16(bsrc, smem + 16384 + wv * 1024);
    GLL16(bsrc + 4096, smem + 20480 + wv * 1024);
    *(uint4*)(smem + wOff0) = packbf8(a00, a01);
    *(uint4*)(smem + wOff1) = packbf8(a10, a11);
  }
  __syncthreads();

#pragma unroll 1
  for (int kt = 0; kt < 16; ++kt) {
    const int cur = kt & 1;
    const char* bufA = smem + cur * 8192;
    const char* bufB = smem + 16384 + cur * 8192;
    char* nA = smem + (cur ^ 1) * 8192;
    char* nB = smem + 16384 + (cur ^ 1) * 8192;

    float4 a00, a01, a10, a11;
    if (kt < 15) {
      const float* p0 = eR0 + (kt + 1) * 32;
      const float* p1 = eR1 + (kt + 1) * 32;
      a00 = *(const float4*)p0;
      a01 = *(const float4*)(p0 + 4);
      a10 = *(const float4*)p1;
      a11 = *(const float4*)(p1 + 4);
      GLL16(bsrc + (size_t)(kt + 1) * 8192, nB + wv * 1024);
      GLL16(bsrc + (size_t)(kt + 1) * 8192 + 4096, nB + 4096 + wv * 1024);
    }

    short8 aF[4], bF[4];
#pragma unroll
    for (int q = 0; q < 4; ++q) aF[q] = *(const short8*)(bufA + aOff[q]);
#pragma unroll
    for (int q = 0; q < 4; ++q) bF[q] = *(const short8*)(bufB + bOff[q]);
#pragma unroll
    for (int qm = 0; qm < 4; ++qm)
#pragma unroll
      for (int qn = 0; qn < 4; ++qn)
        acc[qm][qn] = MFMA16(aF[qm], bF[qn], acc[qm][qn]);

    if (kt < 15) {
      *(uint4*)(nA + wOff0) = packbf8(a00, a01);
      *(uint4*)(nA + wOff1) = packbf8(a10, a11);
    }
    __syncthreads();
  }

  // ---- conv MFMA step (K=32, upper 16 k zero): A=conv feats, B=Watt
  {
    short8 zf;
#pragma unroll
    for (int i = 0; i < 8; ++i) zf[i] = 0;
    short8 cf[4], wf[4];
#pragma unroll
    for (int q = 0; q < 4; ++q) { cf[q] = zf; wf[q] = zf; }
    if (lg < 2) {
#pragma unroll
      for (int q = 0; q < 4; ++q) {
        const int row = m0 + wm * 64 + q * 16 + l15;
        cf[q] = *(const short8*)(convpad + (size_t)row * 128 + h * 32 + lg * 16);
        const int col = wn * 64 + q * 16 + l15;
        wf[q] = *(const short8*)(wattb2 + ((size_t)h * 128 + col) * 32 + lg * 16);
      }
    }
#pragma unroll
    for (int qm = 0; qm < 4; ++qm)
#pragma unroll
      for (int qn = 0; qn < 4; ++qn)
        acc[qm][qn] = MFMA16(cf[qm], wf[qn], acc[qm][qn]);
  }

  // ---- epilogue: + addv, tanh, dot gv, 16-lane reduce -> P, cross-wave sum
  {
    const unsigned b0w = (unsigned)m0 / 4000u;
    const unsigned b1w = (unsigned)(m0 + 127) / 4000u;
    float av0[4], av1[4], gvr[4];
#pragma unroll
    for (int qn = 0; qn < 4; ++qn) {
      const int col = wn * 64 + qn * 16 + l15;
      const int i0 = (int)b0w * 512 + h * 128 + col;
      const int i1 = (int)b1w * 512 + h * 128 + col;
      av0[qn] = addv4[i0] + addv4[8192 + i0] + addv4[16384 + i0] + addv4[24576 + i0];
      av1[qn] = addv4[i1] + addv4[8192 + i1] + addv4[16384 + i1] + addv4[24576 + i1];
      gvr[qn] = gv[h * 128 + col];
    }
    float* Pb = (float*)smem;  // reuse bufA region (all LDS reads done)
#pragma unroll
    for (int qm = 0; qm < 4; ++qm) {
#pragma unroll
      for (int r = 0; r < 4; ++r) {
        const int rowLocal = qm * 16 + lg * 4 + r;      // within wave's 64
        const unsigned brow = (unsigned)(m0 + wm * 64 + rowLocal);
        const unsigned bb = brow / 4000u;
        const int sel = (bb != b0w);
        float s = 0.f;
#pragma unroll
        for (int qn = 0; qn < 4; ++qn)
          s += gvr[qn] * tanh_fast(acc[qm][qn][r] + (sel ? av1[qn] : av0[qn]));
        s += __shfl_xor(s, 1);
        s += __shfl_xor(s, 2);
        s += __shfl_xor(s, 4);
        s += __shfl_xor(s, 8);
        if (l15 == 0) Pb[(wm * 2 + wn) * 64 + rowLocal] = s;
      }
    }
  }
  __syncthreads();
  if (tid < 128) {
    const float* Pb = (const float*)smem;
    const int wmf = tid >> 6, r64 = tid & 63;
    const float ev = Pb[(wmf * 2 + 0) * 64 + r64] + Pb[(wmf * 2 + 1) * 64 + r64];
    const unsigned brow = (unsigned)(m0 + tid);
    const unsigned bb = brow / 4000u;
    const unsigned tt = brow - bb * 4000u;
    e_out[((size_t)bb * H_ + h) * T_ + tt] = ev;
  }
}

// ---------------------------------------------------------------------------
__global__ __launch_bounds__(256) void k_msum(const float* __restrict__ e_in,
                                              float2* __restrict__ msum) {
  const int bh = blockIdx.x;
  const float* er = e_in + (size_t)bh * T_;
  __shared__ float red[256];
  const int tid = threadIdx.x;
  float m = -1e30f;
  for (int t = tid; t < T_; t += 256) m = fmaxf(m, er[t]);
  red[tid] = m;
  __syncthreads();
  for (int s = 128; s > 0; s >>= 1) {
    if (tid < s) red[tid] = fmaxf(red[tid], red[tid + s]);
    __syncthreads();
  }
  m = red[0];
  __syncthreads();
  float sum = 0.f;
  for (int t = tid; t < T_; t += 256) sum += __expf(er[t] - m);
  red[tid] = sum;
  __syncthreads();
  for (int s = 128; s > 0; s >>= 1) {
    if (tid < s) red[tid] += red[tid + s];
    __syncthreads();
  }
  if (tid == 0) msum[bh] = make_float2(m, 1.0f / red[0]);
}

// ---------------------------------------------------------------------------
__global__ __launch_bounds__(128) void k_ctx(const float* __restrict__ enc,
                                             const float* __restrict__ e_in,
                                             const float2* __restrict__ msum,
                                             float* __restrict__ wout,
                                             float* __restrict__ partial) {
  const int b = blockIdx.x, tc = blockIdx.y;
  const int t0 = tc * CH_;
  const int tid = threadIdx.x;
  __shared__ float wls[H_ * CH_];
  for (int i = tid; i < H_ * CH_; i += 128) {
    const int h = i / CH_, tt = i - h * CH_;
    const float2 ms = msum[b * H_ + h];
    const float w = __expf(e_in[((size_t)b * H_ + h) * T_ + t0 + tt] - ms.x) * ms.y;
    wls[i] = w;
    wout[((size_t)h * B_ + b) * T_ + t0 + tt] = w;
  }
  __syncthreads();
  float4 a0 = {0,0,0,0}, a1 = {0,0,0,0}, a2 = {0,0,0,0}, a3 = {0,0,0,0};
  const float4* enc4 = (const float4*)enc;
  const size_t ebase = ((size_t)b * T_ + t0) * 128 + tid;
#pragma unroll 8
  for (int tt = 0; tt < CH_; ++tt) {
    const float4 x = enc4[ebase + (size_t)tt * 128];
    const float w0 = wls[tt], w1 = wls[CH_ + tt], w2 = wls[2 * CH_ + tt], w3 = wls[3 * CH_ + tt];
    a0.x += w0 * x.x; a0.y += w0 * x.y; a0.z += w0 * x.z; a0.w += w0 * x.w;
    a1.x += w1 * x.x; a1.y += w1 * x.y; a1.z += w1 * x.z; a1.w += w1 * x.w;
    a2.x += w2 * x.x; a2.y += w2 * x.y; a2.z += w2 * x.z; a2.w += w2 * x.w;
    a3.x += w3 * x.x; a3.y += w3 * x.y; a3.z += w3 * x.z; a3.w += w3 * x.w;
  }
  float4* p4 = (float4*)partial;
  const size_t pbase = (((size_t)tc * B_ + b) * H_) * 128 + tid;
  p4[pbase] = a0;
  p4[pbase + 128] = a1;
  p4[pbase + 256] = a2;
  p4[pbase + 384] = a3;
}

// ---------------------------------------------------------------------------
__global__ __launch_bounds__(256) void k_out_part(const float* __restrict__ partial,
                                                  const float* __restrict__ Wo,
                                                  float* __restrict__ p2) {
  const int b = blockIdx.x;
  const int o = blockIdx.y * 256 + threadIdx.x;
  const int kc = blockIdx.z;
  __shared__ float cS[256];
  const int he0 = kc * 256;
  {
    float s = 0.f;
#pragma unroll
    for (int tc = 0; tc < TC_; ++tc)
      s += partial[((size_t)tc * B_ + b) * (H_ * E_) + he0 + threadIdx.x];
    cS[threadIdx.x] = s;
  }
  __syncthreads();
  float s = 0.f;
#pragma unroll 8
  for (int i = 0; i < 256; ++i) s += cS[i] * Wo[(size_t)(he0 + i) * O_ + o];
  p2[((size_t)kc * B_ + b) * O_ + o] = s;
}

__global__ __launch_bounds__(512) void k_out_fin(const float* __restrict__ p2,
                                                 const float* __restrict__ bo,
                                                 float* __restrict__ out) {
  const int b = blockIdx.x, o = threadIdx.x;
  float s = bo[o];
#pragma unroll
  for (int kc = 0; kc < 8; ++kc) s += p2[((size_t)kc * B_ + b) * O_ + o];
  out[b * O_ + o] = s;
}

// ---------------------------------------------------------------------------
extern "C" void kernel_launch(void* const* d_in, const int* in_sizes, int n_in,
                              void* d_out, int out_size, void* d_ws, size_t ws_size,
                              hipStream_t stream) {
  (void)in_sizes; (void)n_in; (void)out_size; (void)ws_size;
  const float* enc      = (const float*)d_in[0];
  // d_in[1] = enc_len : unused by the reference
  const float* dec_z    = (const float*)d_in[2];
  const float* att_prev = (const float*)d_in[3];
  const float* Wenc     = (const float*)d_in[4];
  const float* benc     = (const float*)d_in[5];
  const float* Wdec     = (const float*)d_in[6];
  const float* Watt     = (const float*)d_in[7];
  const float* conv_w   = (const float*)d_in[8];
  const float* gv       = (const float*)d_in[9];
  const float* Wo       = (const float*)d_in[10];
  const float* bo       = (const float*)d_in[11];

  float* out  = (float*)d_out;
  float* wout = out + B_ * O_;  // ws [H,B,T]

  char* wsb = (char*)d_ws;
  float*  e_buf   = (float*)(wsb);               // 1,024,000 B
  char*   convpad = wsb + 1024000;               // 8,192,000 B
  char*   wbs2    = wsb + 9216000;               //   524,288 B
  char*   wattb2  = wsb + 9740288;               //    16,384 B
  float*  addv4   = (float*)(wsb + 9756672);     //   131,072 B
  float2* msum    = (float2*)(wsb + 9887744);    //       512 B
  float*  partial = (float*)(wsb + 9888256);     // 6,553,600 B
  float*  p2      = (float*)(wsb + 16441856);    //   262,144 B

  hipLaunchKernelGGL(k_prep, dim3(257), dim3(256), 0, stream,
                     Wenc, Watt, dec_z, Wdec, benc, wbs2, wattb2, addv4);
  hipLaunchKernelGGL(k_conv, dim3(B_ * H_, 16), dim3(256), 0, stream, att_prev, conv_w, convpad);
  hipLaunchKernelGGL(k_fused_e_mfma, dim3(H_, 500), dim3(256), 0, stream,
                     enc, wbs2, convpad, wattb2, addv4, gv, e_buf);
  hipLaunchKernelGGL(k_msum, dim3(B_ * H_), dim3(256), 0, stream, e_buf, msum);
  hipLaunchKernelGGL(k_ctx, dim3(B_, TC_), dim3(128), 0, stream, enc, e_buf, msum, wout, partial);
  hipLaunchKernelGGL(k_out_part, dim3(B_, O_ / 256, 8), dim3(256), 0, stream, partial, Wo, p2);
  hipLaunchKernelGGL(k_out_fin, dim3(B_), dim3(512), 0, stream, p2, bo, out);
}

// Round 11
// 143.234 us; speedup vs baseline: 1.2776x; 1.1618x over previous
//
#include <hip/hip_runtime.h>
#include <hip/hip_bf16.h>

#define H_ 4
#define B_ 16
#define T_ 4000
#define E_ 512
#define D_ 512
#define A_ 128
#define C_ 10
#define K_ 101
#define O_ 512
#define TC_ 50
#define CH_ (T_ / TC_)   // 80

typedef __attribute__((ext_vector_type(4))) float f32x4;
typedef __attribute__((ext_vector_type(8)))  short short8;

#define MFMA16(a, b, c) __builtin_amdgcn_mfma_f32_16x16x32_bf16(a, b, c, 0, 0, 0)

#define GLL16(gp, lp) __builtin_amdgcn_global_load_lds( \
    (const __attribute__((address_space(1))) unsigned int*)(gp), \
    (__attribute__((address_space(3))) unsigned int*)(lp), 16, 0, 0)

static __device__ __forceinline__ unsigned short f2bf(float x) {
  unsigned u = __float_as_uint(x);
  unsigned r = (u + 0x7FFFu + ((u >> 16) & 1u)) >> 16;
  return (unsigned short)r;
}
static __device__ __forceinline__ unsigned pk2(float a, float b) {
  return (unsigned)f2bf(a) | ((unsigned)f2bf(b) << 16);
}
static __device__ __forceinline__ unsigned cvtpk(float lo, float hi) {
  unsigned r;
  asm("v_cvt_pk_bf16_f32 %0, %1, %2" : "=v"(r) : "v"(lo), "v"(hi));
  return r;
}
static __device__ __forceinline__ uint4 packbf8(float4 f0, float4 f1) {
  uint4 u;
  u.x = cvtpk(f0.x, f0.y); u.y = cvtpk(f0.z, f0.w);
  u.z = cvtpk(f1.x, f1.y); u.w = cvtpk(f1.z, f1.w);
  return u;
}
static __device__ __forceinline__ float tanh_fast(float x) {
  return 1.0f - 2.0f / (__expf(2.0f * x) + 1.0f);
}
// data-permutation swizzle: image chunk (row,c) holds data k-block (c^swz(row))
static __device__ __forceinline__ int swz(int r) {
  return (r & 3) ^ ((r >> 2) & 3);
}

// ---------------------------------------------------------------------------
// k_prep: wbs2 [kt][col=512][4 chunks x 16B] kt-major 32KB slabs, data-
// permutation swizzled per col; wattb2 [h][a][16k] plain bf16; addv4 = 4-way
// split-K partials of benc + dec_z@Wdec, [p][b][h][a].
__global__ __launch_bounds__(256) void k_prep(const float* __restrict__ Wenc,
                                              const float* __restrict__ Watt,
                                              const float* __restrict__ dec_z,
                                              const float* __restrict__ Wdec,
                                              const float* __restrict__ benc,
                                              char* __restrict__ wbs2,
                                              char* __restrict__ wattb2,
                                              float* __restrict__ addv4) {
  const int bid = blockIdx.x;
  const int tid = threadIdx.x;
  if (bid < 128) {
    const int c = bid * 256 + tid;       // 16B chunk: [kt][col][cc]
    const int kt = c >> 11;
    const int ci = c & 2047;
    const int col = ci >> 2, cc = ci & 3;
    const int h = col >> 7, a = col & 127;
    const int kk = kt * 32 + ((cc ^ swz(col)) & 3) * 8;
    const float* w = Wenc + ((size_t)h * E_ + kk) * A_ + a;
    uint4 u;
    u.x = pk2(w[0], w[A_]);
    u.y = pk2(w[2 * A_], w[3 * A_]);
    u.z = pk2(w[4 * A_], w[5 * A_]);
    u.w = pk2(w[6 * A_], w[7 * A_]);
    ((uint4*)wbs2)[c] = u;
  } else if (bid == 128) {
#pragma unroll
    for (int q = 0; q < 4; ++q) {
      const int cw = q * 256 + tid;      // [h][col][half] 16B chunks
      const int h = cw >> 8;
      const int rr = cw & 255;
      const int col = rr >> 1, half = rr & 1;
      unsigned short v[8];
#pragma unroll
      for (int j = 0; j < 8; ++j) {
        const int k = half * 8 + j;
        v[j] = (k < C_) ? f2bf(Watt[((size_t)h * C_ + k) * A_ + col]) : (unsigned short)0;
      }
      uint4 u;
      u.x = (unsigned)v[0] | ((unsigned)v[1] << 16);
      u.y = (unsigned)v[2] | ((unsigned)v[3] << 16);
      u.z = (unsigned)v[4] | ((unsigned)v[5] << 16);
      u.w = (unsigned)v[6] | ((unsigned)v[7] << 16);
      ((uint4*)wattb2)[cw] = u;
    }
  } else {
    const int idx = bid - 129;
    const int b = idx >> 3, h = (idx >> 1) & 3, ks = idx & 1;
    const int a = tid & 127, kh = tid >> 7;
    const int p = ks * 2 + kh;
    const int d0 = p * 128;
    const float* z = dec_z + (size_t)b * D_ + d0;
    const float* w = Wdec + ((size_t)h * D_ + d0) * A_ + a;
    float s = (p == 0) ? benc[h * A_ + a] : 0.f;
#pragma unroll 8
    for (int d = 0; d < 128; ++d) s += z[d] * w[(size_t)d * A_];
    addv4[(((size_t)p * B_ + b) * H_ + h) * A_ + a] = s;
  }
}

// ---------------------------------------------------------------------------
__global__ __launch_bounds__(256) void k_conv(const float* __restrict__ att_prev,
                                              const float* __restrict__ conv_w,
                                              char* __restrict__ convpad) {
  const int bh = blockIdx.x;
  const int b = bh / H_, h = bh % H_;
  const int t0 = blockIdx.y * 256;
  __shared__ float ap[256 + K_ - 1 + 3];
  __shared__ float cw[C_ * K_];
  const float* src = att_prev + ((size_t)h * B_ + b) * T_;
  for (int i = threadIdx.x; i < 256 + K_ - 1; i += 256) {
    int tt = t0 - (K_ / 2) + i;
    ap[i] = (tt >= 0 && tt < T_) ? src[tt] : 0.f;
  }
  for (int i = threadIdx.x; i < C_ * K_; i += 256) cw[i] = conv_w[(size_t)h * C_ * K_ + i];
  __syncthreads();
  const int t = t0 + threadIdx.x;
  if (t < T_) {
    float s[C_];
#pragma unroll
    for (int c = 0; c < C_; ++c) s[c] = 0.f;
    for (int k = 0; k < K_; ++k) {
      float apv = ap[threadIdx.x + k];
#pragma unroll
      for (int c = 0; c < C_; ++c) s[c] += cw[c * K_ + k] * apv;
    }
    uint4 u0, u1;
    u0.x = pk2(s[0], s[1]); u0.y = pk2(s[2], s[3]);
    u0.z = pk2(s[4], s[5]); u0.w = pk2(s[6], s[7]);
    u1.x = pk2(s[8], s[9]); u1.y = 0u; u1.z = 0u; u1.w = 0u;
    char* dst = convpad + (size_t)(b * T_ + t) * 128 + h * 32;
    *(uint4*)dst = u0;
    *(uint4*)(dst + 16) = u1;
  }
}

// ---------------------------------------------------------------------------
// Fused MFMA — round-10 engine (16x16x32, 64-AGPR acc, data-perm swizzle),
// heads MERGED so enc is read ONCE (round-10 was fetch-bound: 273MB @3TB/s).
// Block = 64 rows x 512 cols (all 4 heads), 512 thr, 8 waves of 64x64
// (wave wv: head wv>>1, col-half wv&1). Role-split staging:
//   waves 0-3: A (2 enc float4 -> cvt_pk -> 1 ds_write; X-reg prefetch kt+2
//              rides across the barrier via vmcnt(2))
//   waves 4-7: B (8x GLL16/kt from kt-major wbs2 slabs; vmcnt(0) drain)
// LDS 72KB (A 2x4KB + B 2x32KB) -> 2 blocks/CU; VGPR ~115 <= 128 at (512,4).
__global__ __launch_bounds__(512, 4) void k_fused_e_mfma(
    const float* __restrict__ enc,
    const char*  __restrict__ wbs2,
    const char*  __restrict__ convpad,
    const char*  __restrict__ wattb2,
    const float* __restrict__ addv4,
    const float* __restrict__ gv,
    float* __restrict__ e_out) {
  __shared__ char smem[73728];  // A0 0, A1 4096, B0 8192, B1 40960
  const int tid = threadIdx.x;
  const int wv = tid >> 6;
  const int lane = tid & 63, l15 = lane & 15, lg = lane >> 4;
  const int m0 = blockIdx.x * 64;
  const int h = wv >> 1;        // this wave's head
  const bool aRole = (wv < 4);

  f32x4 acc[4][4];
#pragma unroll
  for (int i = 0; i < 4; ++i)
#pragma unroll
    for (int j = 0; j < 4; ++j) acc[i][j] = (f32x4){0.f, 0.f, 0.f, 0.f};

  // fragment read offsets
  int aOff[4], bOff[4];
#pragma unroll
  for (int q = 0; q < 4; ++q) {
    const int row = q * 16 + l15;
    aOff[q] = row * 64 + (((lg ^ swz(row)) & 3) << 4);
    const int col = wv * 64 + q * 16 + l15;
    bOff[q] = col * 64 + (((lg ^ swz(col)) & 3) << 4);
  }

  // A staging geometry (threads 0..255)
  const int arow = tid >> 2, ac = tid & 3;
  const int ks = ((ac ^ swz(arow)) & 3) * 8;
  const float* eR = enc + (size_t)(m0 + arow) * E_ + ks;
  const int wOff = arow * 64 + ac * 16;
  // B staging geometry (waves 4..7)
  const char* bsrc = wbs2 + (size_t)(wv - 4) * 8192 + lane * 16;
  char* bdstBase = smem + 8192 + (wv - 4) * 8192;

  float4 X0, X1;

  // ---- prologue: A(0)+X=A(1) | B(0)
  if (aRole) {
    float4 c0 = *(const float4*)eR;
    float4 c1 = *(const float4*)(eR + 4);
    X0 = *(const float4*)(eR + 32);
    X1 = *(const float4*)(eR + 36);
    *(uint4*)(smem + wOff) = packbf8(c0, c1);
    asm volatile("s_waitcnt vmcnt(2) lgkmcnt(0)" ::: "memory");
  } else {
#pragma unroll
    for (int i = 0; i < 8; ++i)
      GLL16(bsrc + i * 1024, bdstBase + i * 1024);
    asm volatile("s_waitcnt vmcnt(0) lgkmcnt(0)" ::: "memory");
  }
  __builtin_amdgcn_sched_barrier(0);
  __builtin_amdgcn_s_barrier();

#pragma unroll 1
  for (int kt = 0; kt < 16; ++kt) {
    const int cur = kt & 1;
    const char* bufA = smem + cur * 4096;
    const char* bufB = smem + 8192 + cur * 32768;

    // (1) B prefetch kt+1 (waves 4-7)
    if (!aRole && kt < 15) {
      const char* s = bsrc + (size_t)(kt + 1) * 32768;
      char* d = smem + 8192 + (cur ^ 1) * 32768 + (wv - 4) * 8192;
#pragma unroll
      for (int i = 0; i < 8; ++i)
        GLL16(s + i * 1024, d + i * 1024);
    }
    __builtin_amdgcn_sched_barrier(0);

    // (2) frags + 16 MFMA
    short8 aF[4];
#pragma unroll
    for (int q = 0; q < 4; ++q) aF[q] = *(const short8*)(bufA + aOff[q]);
#pragma unroll
    for (int qn = 0; qn < 4; ++qn) {
      short8 bF = *(const short8*)(bufB + bOff[qn]);
#pragma unroll
      for (int qm = 0; qm < 4; ++qm)
        acc[qm][qn] = MFMA16(aF[qm], bF, acc[qm][qn]);
    }

    // (3) A write kt+1 from X; reload X = enc(kt+2)
    if (aRole) {
      if (kt < 15)
        *(uint4*)(smem + (cur ^ 1) * 4096 + wOff) = packbf8(X0, X1);
      if (kt < 14) {
        X0 = *(const float4*)(eR + (kt + 2) * 32);
        X1 = *(const float4*)(eR + (kt + 2) * 32 + 4);
      }
    }

    // (4) role-counted barrier
    if (kt < 14) {
      if (aRole)
        asm volatile("s_waitcnt vmcnt(2) lgkmcnt(0)" ::: "memory");
      else
        asm volatile("s_waitcnt vmcnt(0) lgkmcnt(0)" ::: "memory");
    } else {
      asm volatile("s_waitcnt vmcnt(0) lgkmcnt(0)" ::: "memory");
    }
    __builtin_amdgcn_sched_barrier(0);
    __builtin_amdgcn_s_barrier();
  }

  // ---- conv MFMA step (K=32, upper 16 k zero)
  {
    short8 zf;
#pragma unroll
    for (int i = 0; i < 8; ++i) zf[i] = 0;
    short8 cf[4], wf[4];
#pragma unroll
    for (int q = 0; q < 4; ++q) { cf[q] = zf; wf[q] = zf; }
    if (lg < 2) {
#pragma unroll
      for (int q = 0; q < 4; ++q) {
        const int row = m0 + q * 16 + l15;
        cf[q] = *(const short8*)(convpad + (size_t)row * 128 + h * 32 + lg * 16);
        const int col = (wv & 1) * 64 + q * 16 + l15;   // head-local col
        wf[q] = *(const short8*)(wattb2 + ((size_t)h * 128 + col) * 32 + lg * 16);
      }
    }
#pragma unroll
    for (int qm = 0; qm < 4; ++qm)
#pragma unroll
      for (int qn = 0; qn < 4; ++qn)
        acc[qm][qn] = MFMA16(cf[qm], wf[qn], acc[qm][qn]);
  }

  // ---- epilogue: + addv, tanh, dot gv, 16-lane reduce -> Pb, cross-wave sum
  {
    const unsigned b0w = (unsigned)m0 / 4000u;
    const unsigned b1w = (unsigned)(m0 + 63) / 4000u;
    float av0[4], av1[4], gvr[4];
#pragma unroll
    for (int qn = 0; qn < 4; ++qn) {
      const int col = (wv & 1) * 64 + qn * 16 + l15;
      const int i0 = (int)b0w * 512 + h * 128 + col;
      const int i1 = (int)b1w * 512 + h * 128 + col;
      av0[qn] = addv4[i0] + addv4[8192 + i0] + addv4[16384 + i0] + addv4[24576 + i0];
      av1[qn] = addv4[i1] + addv4[8192 + i1] + addv4[16384 + i1] + addv4[24576 + i1];
      gvr[qn] = gv[h * 128 + col];
    }
    float* Pb = (float*)smem;   // 8 waves x 64 rows (A region, reads all done)
#pragma unroll
    for (int qm = 0; qm < 4; ++qm) {
#pragma unroll
      for (int r = 0; r < 4; ++r) {
        const int rowLocal = qm * 16 + lg * 4 + r;
        const unsigned brow = (unsigned)(m0 + rowLocal);
        const unsigned bb = brow / 4000u;
        const int sel = (bb != b0w);
        float s = 0.f;
#pragma unroll
        for (int qn = 0; qn < 4; ++qn)
          s += gvr[qn] * tanh_fast(acc[qm][qn][r] + (sel ? av1[qn] : av0[qn]));
        s += __shfl_xor(s, 1);
        s += __shfl_xor(s, 2);
        s += __shfl_xor(s, 4);
        s += __shfl_xor(s, 8);
        if (l15 == 0) Pb[wv * 64 + rowLocal] = s;
      }
    }
  }
  __syncthreads();
  if (tid < 256) {
    const float* Pb = (const float*)smem;
    const int hh = tid >> 6, r = tid & 63;
    const float ev = Pb[(hh * 2) * 64 + r] + Pb[(hh * 2 + 1) * 64 + r];
    const unsigned brow = (unsigned)(m0 + r);
    const unsigned bb = brow / 4000u;
    const unsigned tt = brow - bb * 4000u;
    e_out[((size_t)bb * H_ + hh) * T_ + tt] = ev;
  }
}

// ---------------------------------------------------------------------------
__global__ __launch_bounds__(256) void k_msum(const float* __restrict__ e_in,
                                              float2* __restrict__ msum) {
  const int bh = blockIdx.x;
  const float* er = e_in + (size_t)bh * T_;
  __shared__ float red[256];
  const int tid = threadIdx.x;
  float m = -1e30f;
  for (int t = tid; t < T_; t += 256) m = fmaxf(m, er[t]);
  red[tid] = m;
  __syncthreads();
  for (int s = 128; s > 0; s >>= 1) {
    if (tid < s) red[tid] = fmaxf(red[tid], red[tid + s]);
    __syncthreads();
  }
  m = red[0];
  __syncthreads();
  float sum = 0.f;
  for (int t = tid; t < T_; t += 256) sum += __expf(er[t] - m);
  red[tid] = sum;
  __syncthreads();
  for (int s = 128; s > 0; s >>= 1) {
    if (tid < s) red[tid] += red[tid + s];
    __syncthreads();
  }
  if (tid == 0) msum[bh] = make_float2(m, 1.0f / red[0]);
}

// ---------------------------------------------------------------------------
__global__ __launch_bounds__(128) void k_ctx(const float* __restrict__ enc,
                                             const float* __restrict__ e_in,
                                             const float2* __restrict__ msum,
                                             float* __restrict__ wout,
                                             float* __restrict__ partial) {
  const int b = blockIdx.x, tc = blockIdx.y;
  const int t0 = tc * CH_;
  const int tid = threadIdx.x;
  __shared__ float wls[H_ * CH_];
  for (int i = tid; i < H_ * CH_; i += 128) {
    const int h = i / CH_, tt = i - h * CH_;
    const float2 ms = msum[b * H_ + h];
    const float w = __expf(e_in[((size_t)b * H_ + h) * T_ + t0 + tt] - ms.x) * ms.y;
    wls[i] = w;
    wout[((size_t)h * B_ + b) * T_ + t0 + tt] = w;
  }
  __syncthreads();
  float4 a0 = {0,0,0,0}, a1 = {0,0,0,0}, a2 = {0,0,0,0}, a3 = {0,0,0,0};
  const float4* enc4 = (const float4*)enc;
  const size_t ebase = ((size_t)b * T_ + t0) * 128 + tid;
#pragma unroll 8
  for (int tt = 0; tt < CH_; ++tt) {
    const float4 x = enc4[ebase + (size_t)tt * 128];
    const float w0 = wls[tt], w1 = wls[CH_ + tt], w2 = wls[2 * CH_ + tt], w3 = wls[3 * CH_ + tt];
    a0.x += w0 * x.x; a0.y += w0 * x.y; a0.z += w0 * x.z; a0.w += w0 * x.w;
    a1.x += w1 * x.x; a1.y += w1 * x.y; a1.z += w1 * x.z; a1.w += w1 * x.w;
    a2.x += w2 * x.x; a2.y += w2 * x.y; a2.z += w2 * x.z; a2.w += w2 * x.w;
    a3.x += w3 * x.x; a3.y += w3 * x.y; a3.z += w3 * x.z; a3.w += w3 * x.w;
  }
  float4* p4 = (float4*)partial;
  const size_t pbase = (((size_t)tc * B_ + b) * H_) * 128 + tid;
  p4[pbase] = a0;
  p4[pbase + 128] = a1;
  p4[pbase + 256] = a2;
  p4[pbase + 384] = a3;
}

// ---------------------------------------------------------------------------
__global__ __launch_bounds__(256) void k_out_part(const float* __restrict__ partial,
                                                  const float* __restrict__ Wo,
                                                  float* __restrict__ p2) {
  const int b = blockIdx.x;
  const int o = blockIdx.y * 256 + threadIdx.x;
  const int kc = blockIdx.z;
  __shared__ float cS[256];
  const int he0 = kc * 256;
  {
    float s = 0.f;
#pragma unroll
    for (int tc = 0; tc < TC_; ++tc)
      s += partial[((size_t)tc * B_ + b) * (H_ * E_) + he0 + threadIdx.x];
    cS[threadIdx.x] = s;
  }
  __syncthreads();
  float s = 0.f;
#pragma unroll 8
  for (int i = 0; i < 256; ++i) s += cS[i] * Wo[(size_t)(he0 + i) * O_ + o];
  p2[((size_t)kc * B_ + b) * O_ + o] = s;
}

__global__ __launch_bounds__(512) void k_out_fin(const float* __restrict__ p2,
                                                 const float* __restrict__ bo,
                                                 float* __restrict__ out) {
  const int b = blockIdx.x, o = threadIdx.x;
  float s = bo[o];
#pragma unroll
  for (int kc = 0; kc < 8; ++kc) s += p2[((size_t)kc * B_ + b) * O_ + o];
  out[b * O_ + o] = s;
}

// ---------------------------------------------------------------------------
extern "C" void kernel_launch(void* const* d_in, const int* in_sizes, int n_in,
                              void* d_out, int out_size, void* d_ws, size_t ws_size,
                              hipStream_t stream) {
  (void)in_sizes; (void)n_in; (void)out_size; (void)ws_size;
  const float* enc      = (const float*)d_in[0];
  // d_in[1] = enc_len : unused by the reference
  const float* dec_z    = (const float*)d_in[2];
  const float* att_prev = (const float*)d_in[3];
  const float* Wenc     = (const float*)d_in[4];
  const float* benc     = (const float*)d_in[5];
  const float* Wdec     = (const float*)d_in[6];
  const float* Watt     = (const float*)d_in[7];
  const float* conv_w   = (const float*)d_in[8];
  const float* gv       = (const float*)d_in[9];
  const float* Wo       = (const float*)d_in[10];
  const float* bo       = (const float*)d_in[11];

  float* out  = (float*)d_out;
  float* wout = out + B_ * O_;  // ws [H,B,T]

  char* wsb = (char*)d_ws;
  float*  e_buf   = (float*)(wsb);               // 1,024,000 B
  char*   convpad = wsb + 1024000;               // 8,192,000 B
  char*   wbs2    = wsb + 9216000;               //   524,288 B
  char*   wattb2  = wsb + 9740288;               //    16,384 B
  float*  addv4   = (float*)(wsb + 9756672);     //   131,072 B
  float2* msum    = (float2*)(wsb + 9887744);    //       512 B
  float*  partial = (float*)(wsb + 9888256);     // 6,553,600 B
  float*  p2      = (float*)(wsb + 16441856);    //   262,144 B

  hipLaunchKernelGGL(k_prep, dim3(257), dim3(256), 0, stream,
                     Wenc, Watt, dec_z, Wdec, benc, wbs2, wattb2, addv4);
  hipLaunchKernelGGL(k_conv, dim3(B_ * H_, 16), dim3(256), 0, stream, att_prev, conv_w, convpad);
  hipLaunchKernelGGL(k_fused_e_mfma, dim3(1000), dim3(512), 0, stream,
                     enc, wbs2, convpad, wattb2, addv4, gv, e_buf);
  hipLaunchKernelGGL(k_msum, dim3(B_ * H_), dim3(256), 0, stream, e_buf, msum);
  hipLaunchKernelGGL(k_ctx, dim3(B_, TC_), dim3(128), 0, stream, enc, e_buf, msum, wout, partial);
  hipLaunchKernelGGL(k_out_part, dim3(B_, O_ / 256, 8), dim3(256), 0, stream, partial, Wo, p2);
  hipLaunchKernelGGL(k_out_fin, dim3(B_), dim3(512), 0, stream, p2, bo, out);
}